// Round 4
// baseline (298.819 us; speedup 1.0000x reference)
//
#include <hip/hip_runtime.h>

typedef float f2 __attribute__((ext_vector_type(2)));
#define AS4 __attribute__((address_space(4)))

// ---- prepared weight buffer layout (float offsets in d_ws) ----
// All matrices stored TRANSPOSED + padded: wT[k][16], wT[k][j] = f(W[j][k]), j=15 -> 0
constexpr int OFF_YW0 = 0;       // IN=8   128  softplus'ed
constexpr int OFF_YWS = 128;     // 3x15x16 720 softplus'ed
constexpr int OFF_ZW0 = 848;     // 128
constexpr int OFF_ZWS = 976;     // 720
constexpr int OFF_TW0 = 1696;    // IN=4    64  softplus'ed
constexpr int OFF_TWS = 1760;    // 720  softplus'ed
constexpr int OFF_X0W = 2480;    // IN=16  256
constexpr int OFF_Y0W = 2736;    // 128  softplus'ed
constexpr int OFF_Z0W = 2864;    // 128
constexpr int OFF_T0W = 2992;    //  64  softplus'ed
constexpr int OFF_XWS = 3056;    // 720  softplus'ed
constexpr int OFF_XSW = 3776;    // 3x16x16 768
constexpr int OFF_XYW = 4544;    // 720  softplus'ed
constexpr int OFF_XZW = 5264;    // 720
constexpr int OFF_XTW = 5984;    // 720  softplus'ed
constexpr int OFF_FW  = 6704;    // 240
constexpr int OFF_YB  = 6944;    // 4x16 padded
constexpr int OFF_ZB  = 7008;    // 64
constexpr int OFF_TB  = 7072;    // 64
constexpr int OFF_XFB = 7136;    // 16 (x0b+y0b+z0b+t0b)
constexpr int OFF_XLB = 7152;    // 3x16 (xb+xsb+xyb+xzb+xtb per iter)
constexpr int OFF_FB  = 7200;    // 16
constexpr int W_TOTAL = 7216;

__device__ __forceinline__ float sp_stable(float v) {
  float ax = __builtin_fabsf(v);
  float e  = __expf(-ax);
  return fmaxf(v, 0.0f) + __logf(1.0f + e);
}

__device__ __forceinline__ float sigmoid_f(float v) {
  return __builtin_amdgcn_rcpf(1.0f + __expf(-v));
}

// ---------------- weight prep: transpose + pad + (optional) softplus -------------
#define TPOSE(DST, SRC, IN, NL, SP)                                              \
  for (int i = tid; i < (NL) * (IN) * 16; i += str) {                            \
    int l = i / ((IN) * 16);                                                     \
    int rem = i - l * (IN) * 16;                                                 \
    int k = rem >> 4, j = rem & 15;                                              \
    float v = (j < 15) ? SRC[(l * 15 + j) * (IN) + k] : 0.0f;                    \
    w[(DST) + i] = ((SP) && j < 15) ? sp_stable(v) : v;                          \
  }

__global__ void prep_kernel(
    const float* __restrict__ yW0, const float* __restrict__ yWs, const float* __restrict__ yb,
    const float* __restrict__ zW0, const float* __restrict__ zWs, const float* __restrict__ zb,
    const float* __restrict__ tW0, const float* __restrict__ tWs, const float* __restrict__ tb,
    const float* __restrict__ x0W, const float* __restrict__ x0b,
    const float* __restrict__ y0W, const float* __restrict__ y0b,
    const float* __restrict__ z0W, const float* __restrict__ z0b,
    const float* __restrict__ t0W, const float* __restrict__ t0b,
    const float* __restrict__ xWs, const float* __restrict__ xb,
    const float* __restrict__ xsW, const float* __restrict__ xsb,
    const float* __restrict__ xyW, const float* __restrict__ xyb,
    const float* __restrict__ xzW, const float* __restrict__ xzb,
    const float* __restrict__ xtW, const float* __restrict__ xtb,
    const float* __restrict__ fW, const float* __restrict__ fb,
    float* __restrict__ w)
{
  const int tid = blockIdx.x * blockDim.x + threadIdx.x;
  const int str = gridDim.x * blockDim.x;
  TPOSE(OFF_YW0, yW0,  8, 1, 1)
  TPOSE(OFF_YWS, yWs, 15, 3, 1)
  TPOSE(OFF_ZW0, zW0,  8, 1, 0)
  TPOSE(OFF_ZWS, zWs, 15, 3, 0)
  TPOSE(OFF_TW0, tW0,  4, 1, 1)
  TPOSE(OFF_TWS, tWs, 15, 3, 1)
  TPOSE(OFF_X0W, x0W, 16, 1, 0)
  TPOSE(OFF_Y0W, y0W,  8, 1, 1)
  TPOSE(OFF_Z0W, z0W,  8, 1, 0)
  TPOSE(OFF_T0W, t0W,  4, 1, 1)
  TPOSE(OFF_XWS, xWs, 15, 3, 1)
  TPOSE(OFF_XSW, xsW, 16, 3, 0)
  TPOSE(OFF_XYW, xyW, 15, 3, 1)
  TPOSE(OFF_XZW, xzW, 15, 3, 0)
  TPOSE(OFF_XTW, xtW, 15, 3, 1)
  TPOSE(OFF_FW,  fW,  15, 1, 0)
  for (int i = tid; i < 64; i += str) { int l = i >> 4, j = i & 15;
    w[OFF_YB + i] = (j < 15) ? yb[l * 15 + j] : 0.0f; }
  for (int i = tid; i < 64; i += str) { int l = i >> 4, j = i & 15;
    w[OFF_ZB + i] = (j < 15) ? zb[l * 15 + j] : 0.0f; }
  for (int i = tid; i < 64; i += str) { int l = i >> 4, j = i & 15;
    w[OFF_TB + i] = (j < 15) ? tb[l * 15 + j] : 0.0f; }
  for (int i = tid; i < 16; i += str)
    w[OFF_XFB + i] = (i < 15) ? (x0b[i] + y0b[i] + z0b[i] + t0b[i]) : 0.0f;
  for (int i = tid; i < 48; i += str) { int l = i >> 4, j = i & 15;
    w[OFF_XLB + i] = (j < 15) ? (xb[l*15+j] + xsb[l*15+j] + xyb[l*15+j] + xzb[l*15+j] + xtb[l*15+j]) : 0.0f; }
  for (int i = tid; i < 16; i += str)
    w[OFF_FB + i] = (i < 15) ? fb[i] : 0.0f;
}

// ---------------- main kernel ------------------------------------------------------
// Weights read through CONSTANT address space (AS4) with wave-uniform addresses ->
// backend selects s_load (SMEM); weights live in SGPRs and feed v_pk_fma_f32 as the
// scalar operand. No divergent control flow anywhere (guard removed; exact grid).
template<int IN>
__device__ __forceinline__ void mv(const AS4 float* Wt,   // IN x 16
                                   const AS4 float* b16,  // 16 padded
                                   const float* in,
                                   f2* acc) {
  const AS4 f2* b2 = (const AS4 f2*)b16;
#pragma unroll
  for (int j2 = 0; j2 < 8; ++j2) acc[j2] = b2[j2];
#pragma unroll
  for (int k = 0; k < IN; ++k) {
    const AS4 f2* row = (const AS4 f2*)(Wt + k * 16);
    f2 inb = {in[k], in[k]};
#pragma unroll
    for (int j2 = 0; j2 < 8; ++j2)
      acc[j2] = __builtin_elementwise_fma(row[j2], inb, acc[j2]);
  }
}

template<int IN>
__device__ __forceinline__ void mv_acc(const AS4 float* Wt,
                                       const float* in,
                                       f2* acc) {
#pragma unroll
  for (int k = 0; k < IN; ++k) {
    const AS4 f2* row = (const AS4 f2*)(Wt + k * 16);
    f2 inb = {in[k], in[k]};
#pragma unroll
    for (int j2 = 0; j2 < 8; ++j2)
      acc[j2] = __builtin_elementwise_fma(row[j2], inb, acc[j2]);
  }
}

__global__ __launch_bounds__(256, 3) void isnn_fwd(
    const float* __restrict__ x0g, const float* __restrict__ y0g,
    const float* __restrict__ z0g, const float* __restrict__ t0g,
    const float* __restrict__ wg,  float* __restrict__ outg)
{
  // NOTE: grid sized exactly n/256 (N = 1048576 = 4096*256) -> no guard, no
  // divergent control flow, required for uniform-load -> SMEM promotion.
  const int r = blockIdx.x * blockDim.x + threadIdx.x;

  const AS4 float* w = (const AS4 float*)(unsigned long long)wg;

  float x0v[16], y0v[8], z0v[8], t0v[4];
#pragma unroll
  for (int k = 0; k < 4; ++k)
    ((float4*)x0v)[k] = ((const float4*)(x0g))[(size_t)r * 4 + k];
#pragma unroll
  for (int k = 0; k < 2; ++k)
    ((float4*)y0v)[k] = ((const float4*)(y0g))[(size_t)r * 2 + k];
#pragma unroll
  for (int k = 0; k < 2; ++k)
    ((float4*)z0v)[k] = ((const float4*)(z0g))[(size_t)r * 2 + k];
  ((float4*)t0v)[0] = ((const float4*)(t0g))[(size_t)r];

  float y[15], z[15], t[15], x[15];
  f2 a[8];

  // ---- y tower
  mv<8>(w + OFF_YW0, w + OFF_YB, y0v, a);
#pragma unroll
  for (int j = 0; j < 15; ++j) y[j] = sp_stable(((const float*)a)[j]);
  for (int i = 0; i < 3; ++i) {
    mv<15>(w + OFF_YWS + i * 240, w + OFF_YB + 16 + i * 16, y, a);
#pragma unroll
    for (int j = 0; j < 15; ++j) y[j] = sp_stable(((const float*)a)[j]);
  }

  // ---- z tower
  mv<8>(w + OFF_ZW0, w + OFF_ZB, z0v, a);
#pragma unroll
  for (int j = 0; j < 15; ++j) z[j] = sigmoid_f(((const float*)a)[j]);
  for (int i = 0; i < 3; ++i) {
    mv<15>(w + OFF_ZWS + i * 240, w + OFF_ZB + 16 + i * 16, z, a);
#pragma unroll
    for (int j = 0; j < 15; ++j) z[j] = sigmoid_f(((const float*)a)[j]);
  }

  // ---- t tower
  mv<4>(w + OFF_TW0, w + OFF_TB, t0v, a);
#pragma unroll
  for (int j = 0; j < 15; ++j) t[j] = sigmoid_f(((const float*)a)[j]);
  for (int i = 0; i < 3; ++i) {
    mv<15>(w + OFF_TWS + i * 240, w + OFF_TB + 16 + i * 16, t, a);
#pragma unroll
    for (int j = 0; j < 15; ++j) t[j] = sigmoid_f(((const float*)a)[j]);
  }

  // ---- x path: first 4-branch block
  mv<16>(w + OFF_X0W, w + OFF_XFB, x0v, a);
  mv_acc<8>(w + OFF_Y0W, y0v, a);
  mv_acc<8>(w + OFF_Z0W, z0v, a);
  mv_acc<4>(w + OFF_T0W, t0v, a);
#pragma unroll
  for (int j = 0; j < 15; ++j) x[j] = sp_stable(((const float*)a)[j]);

  // ---- x path: 3 iterations of 5-branch blocks
  for (int i = 0; i < 3; ++i) {
    mv<15>(w + OFF_XWS + i * 240, w + OFF_XLB + i * 16, x, a);
    mv_acc<16>(w + OFF_XSW + i * 256, x0v, a);
    mv_acc<15>(w + OFF_XYW + i * 240, y, a);
    mv_acc<15>(w + OFF_XZW + i * 240, z, a);
    mv_acc<15>(w + OFF_XTW + i * 240, t, a);
#pragma unroll
    for (int j = 0; j < 15; ++j) x[j] = sp_stable(((const float*)a)[j]);
  }

  // ---- final linear
  mv<15>(w + OFF_FW, w + OFF_FB, x, a);

  // ---- store 15 floats (4B-aligned vector stores)
  typedef float f4u __attribute__((ext_vector_type(4), aligned(4)));
  typedef float f2u __attribute__((ext_vector_type(2), aligned(4)));
  const float* af = (const float*)a;
  float* orow = outg + (size_t)r * 15;
  ((f4u*)orow)[0] = f4u{af[0], af[1], af[2], af[3]};
  ((f4u*)orow)[1] = f4u{af[4], af[5], af[6], af[7]};
  ((f4u*)orow)[2] = f4u{af[8], af[9], af[10], af[11]};
  *(f2u*)(orow + 12) = f2u{af[12], af[13]};
  orow[14] = af[14];
}

extern "C" void kernel_launch(void* const* d_in, const int* in_sizes, int n_in,
                              void* d_out, int out_size, void* d_ws, size_t ws_size,
                              hipStream_t stream) {
  const float* x0  = (const float*)d_in[0];
  const float* y0  = (const float*)d_in[1];
  const float* z0  = (const float*)d_in[2];
  const float* t0  = (const float*)d_in[3];
  const float* yW0 = (const float*)d_in[4];
  const float* yWs = (const float*)d_in[5];
  const float* yb  = (const float*)d_in[6];
  const float* zW0 = (const float*)d_in[7];
  const float* zWs = (const float*)d_in[8];
  const float* zb  = (const float*)d_in[9];
  const float* tW0 = (const float*)d_in[10];
  const float* tWs = (const float*)d_in[11];
  const float* tb  = (const float*)d_in[12];
  const float* x0W = (const float*)d_in[13];
  const float* x0b = (const float*)d_in[14];
  const float* y0W = (const float*)d_in[15];
  const float* y0b = (const float*)d_in[16];
  const float* z0W = (const float*)d_in[17];
  const float* z0b = (const float*)d_in[18];
  const float* t0W = (const float*)d_in[19];
  const float* t0b = (const float*)d_in[20];
  const float* xWs = (const float*)d_in[21];
  const float* xb  = (const float*)d_in[22];
  const float* xsW = (const float*)d_in[23];
  const float* xsb = (const float*)d_in[24];
  const float* xyW = (const float*)d_in[25];
  const float* xyb = (const float*)d_in[26];
  const float* xzW = (const float*)d_in[27];
  const float* xzb = (const float*)d_in[28];
  const float* xtW = (const float*)d_in[29];
  const float* xtb = (const float*)d_in[30];
  const float* fW  = (const float*)d_in[31];
  const float* fb  = (const float*)d_in[32];

  float* w = (float*)d_ws;

  prep_kernel<<<4, 256, 0, stream>>>(yW0, yWs, yb, zW0, zWs, zb, tW0, tWs, tb,
                                     x0W, x0b, y0W, y0b, z0W, z0b, t0W, t0b,
                                     xWs, xb, xsW, xsb, xyW, xyb, xzW, xzb,
                                     xtW, xtb, fW, fb, w);

  const int n = in_sizes[0] / 16;  // N rows; N = 1048576 = 4096*256 exactly
  const int blocks = n / 256;
  isnn_fwd<<<blocks, 256, 0, stream>>>(x0, y0, z0, t0, w, (float*)d_out);
}

// Round 5
// 198.850 us; speedup vs baseline: 1.5027x; 1.5027x over previous
//
#include <hip/hip_runtime.h>

typedef short  s8v  __attribute__((ext_vector_type(8)));
typedef short  s4v  __attribute__((ext_vector_type(4)));
typedef short  s2v  __attribute__((ext_vector_type(2)));
typedef float  f32x4 __attribute__((ext_vector_type(4)));

#define NSLOT 41
#define NBIAS 17

// ---------- bf16 helpers (manual RNE, no API deps) ----------
__device__ __forceinline__ unsigned short b16hi(float v) {
  unsigned int u = __float_as_uint(v);
  unsigned int r = (u + 0x7FFFu + ((u >> 16) & 1u)) >> 16;
  return (unsigned short)r;
}
__device__ __forceinline__ float b16tof(unsigned short h) {
  return __uint_as_float(((unsigned int)h) << 16);
}
__device__ __forceinline__ unsigned short lobits(float w) {
  unsigned short h = b16hi(w);
  return b16hi(w - b16tof(h));
}

__device__ __forceinline__ float sp_stable(float v) {
  float ax = __builtin_fabsf(v);
  float e  = __expf(-ax);
  return fmaxf(v, 0.0f) + __logf(1.0f + e);
}
__device__ __forceinline__ float sigmoid_f(float v) {
  return __builtin_amdgcn_rcpf(1.0f + __expf(-v));
}

// =====================================================================
// PREP: build B-fragments in frag-linear layout + fused biases.
// Frag layout for mfma_f32_16x16x32_bf16 B-operand: lane l (g=l>>4,n=l&15)
// holds B(k,n) for k = 4g+{0..3} (dwords 0,1) and k = 16+4g+{0..3} (dwords 2,3),
// low 16 bits = even k. Slot table documented inline below.
// =====================================================================
struct P {
  const float *yW0,*yWs,*zW0,*zWs,*tW0,*tWs,*x0W,*y0W,*z0W,*t0W;
  const float *xWs,*xsW,*xyW,*xzW,*xtW,*fW;
};

__device__ unsigned short wbits(int s, int k, int n, const P& p) {
  if (n > 14) return 0;
  // y tower l1: A = [y0;y0] (k0..7 y0, 8..15 y0), half2 zero
  if (s == 0) {
    if (k < 8)  return b16hi(sp_stable(p.yW0[n*8 + k]));
    if (k < 16) return lobits(sp_stable(p.yW0[n*8 + (k-8)]));
    return 0;
  }
  if (s >= 1 && s <= 6) {      // y l2..4 split pairs
    int i = (s-1) >> 1, pr = (s-1) & 1;
    const float* W = p.yWs + i*225;    // 15x15
    if (pr == 0) {
      if (k < 15)           return b16hi(sp_stable(W[n*15 + k]));
      if (k >= 16 && k < 31) return b16hi(sp_stable(W[n*15 + (k-16)]));
      return 0;
    } else {
      if (k < 15) return lobits(sp_stable(W[n*15 + k]));
      return 0;
    }
  }
  if (s == 7) {                // z l1
    if (k < 8)  return b16hi(p.zW0[n*8 + k]);
    if (k < 16) return lobits(p.zW0[n*8 + (k-8)]);
    return 0;
  }
  if (s >= 8 && s <= 10) {     // z l2..4, A=[z;z] dup
    const float* W = p.zWs + (s-8)*225;
    if (k < 15)            return b16hi(W[n*15 + k]);
    if (k >= 16 && k < 31) return lobits(W[n*15 + (k-16)]);
    return 0;
  }
  if (s == 11) {               // t l1: A delivers t0[k&3] for k<8
    if (k < 4) return b16hi(sp_stable(p.tW0[n*4 + k]));
    if (k < 8) return lobits(sp_stable(p.tW0[n*4 + (k-4)]));
    return 0;
  }
  if (s >= 12 && s <= 14) {    // t l2..4 dup
    const float* W = p.tWs + (s-12)*225;
    if (k < 15)            return b16hi(sp_stable(W[n*15 + k]));
    if (k >= 16 && k < 31) return lobits(sp_stable(W[n*15 + (k-16)]));
    return 0;
  }
  if (s == 15) {               // first block: x0 branch, A=[x0;x0]
    if (k < 16) return b16hi(p.x0W[n*16 + k]);
    return lobits(p.x0W[n*16 + (k-16)]);
  }
  if (s == 16) {               // first block: [y0|z0] dup
    if (k < 8)  return b16hi(sp_stable(p.y0W[n*8 + k]));
    if (k < 16) return b16hi(p.z0W[n*8 + (k-8)]);
    if (k < 24) return lobits(sp_stable(p.y0W[n*8 + (k-16)]));
    return lobits(p.z0W[n*8 + (k-24)]);
  }
  if (s == 17) {               // first block: t0
    if (k < 4) return b16hi(sp_stable(p.t0W[n*4 + k]));
    if (k < 8) return lobits(sp_stable(p.t0W[n*4 + (k-4)]));
    return 0;
  }
  if (s >= 18 && s <= 38) {    // x iters
    int i = (s-18) / 7, r = (s-18) % 7;
    if (r == 0) { const float* W = p.xWs + i*225;
      if (k < 15)            return b16hi(sp_stable(W[n*15+k]));
      if (k >= 16 && k < 31) return b16hi(sp_stable(W[n*15+(k-16)]));
      return 0; }
    if (r == 1) { const float* W = p.xWs + i*225;
      if (k < 15) return lobits(sp_stable(W[n*15+k]));
      return 0; }
    if (r == 2) { const float* W = p.xsW + i*240;   // 15x16
      if (k < 16) return b16hi(W[n*16+k]);
      return lobits(W[n*16+(k-16)]); }
    if (r == 3) { const float* W = p.xyW + i*225;
      if (k < 15)            return b16hi(sp_stable(W[n*15+k]));
      if (k >= 16 && k < 31) return b16hi(sp_stable(W[n*15+(k-16)]));
      return 0; }
    if (r == 4) { const float* W = p.xyW + i*225;
      if (k < 15) return lobits(sp_stable(W[n*15+k]));
      return 0; }
    if (r == 5) { const float* W = p.xzW + i*225;
      if (k < 15)            return b16hi(W[n*15+k]);
      if (k >= 16 && k < 31) return lobits(W[n*15+(k-16)]);
      return 0; }
    { const float* W = p.xtW + i*225;
      if (k < 15)            return b16hi(sp_stable(W[n*15+k]));
      if (k >= 16 && k < 31) return lobits(sp_stable(W[n*15+(k-16)]));
      return 0; }
  }
  if (s == 39) {               // final pair1
    if (k < 15)            return b16hi(p.fW[n*15+k]);
    if (k >= 16 && k < 31) return b16hi(p.fW[n*15+(k-16)]);
    return 0;
  }
  // s == 40: final pair2
  if (k < 15) return lobits(p.fW[n*15+k]);
  return 0;
}

__global__ void prep_kernel(
    const float* yW0, const float* yWs, const float* yb,
    const float* zW0, const float* zWs, const float* zb,
    const float* tW0, const float* tWs, const float* tb,
    const float* x0W, const float* x0b, const float* y0W, const float* y0b,
    const float* z0W, const float* z0b, const float* t0W, const float* t0b,
    const float* xWs, const float* xb,  const float* xsW, const float* xsb,
    const float* xyW, const float* xyb, const float* xzW, const float* xzb,
    const float* xtW, const float* xtb, const float* fW,  const float* fb,
    unsigned int* Bbuf, float* biasb)
{
  P p{yW0,yWs,zW0,zWs,tW0,tWs,x0W,y0W,z0W,t0W,xWs,xsW,xyW,xzW,xtW,fW};
  const int tid = blockIdx.x * blockDim.x + threadIdx.x;
  const int str = gridDim.x * blockDim.x;
  // frag dwords: idx -> s, lane, dword
  for (int idx = tid; idx < NSLOT*64*4; idx += str) {
    int s = idx >> 8, rem = idx & 255, l = rem >> 2, d = rem & 3;
    int g = l >> 4, n = l & 15;
    int kb = (d < 2) ? (4*g + 2*d) : (16 + 4*g + 2*(d-2));
    unsigned int v0 = wbits(s, kb,   n, p);
    unsigned int v1 = wbits(s, kb+1, n, p);
    Bbuf[idx] = v0 | (v1 << 16);
  }
  // biases
  for (int idx = tid; idx < NBIAS*16; idx += str) {
    int b = idx >> 4, n = idx & 15;
    float v = 0.f;
    if (n < 15) {
      if (b < 4)        v = yb[b*15 + n];
      else if (b < 8)   v = zb[(b-4)*15 + n];
      else if (b < 12)  v = tb[(b-8)*15 + n];
      else if (b == 12) v = x0b[n] + y0b[n] + z0b[n] + t0b[n];
      else if (b < 16)  { int i = b - 13;
        v = xb[i*15+n] + xsb[i*15+n] + xyb[i*15+n] + xzb[i*15+n] + xtb[i*15+n]; }
      else              v = fb[n];
    }
    biasb[idx] = v;
  }
}

// =====================================================================
// MAIN: 4 waves/block, 1 tile (16 rows) per wave at a time, 4 tiles/wave.
// Activation images per wave in LDS: [m][k] bf16, stride 20 (conflict-free).
// =====================================================================
#define STR 20

__device__ __forceinline__ s4v rd4(const short* img, int m, int col) {
  return *(const s4v*)(img + m*STR + col);
}
__device__ __forceinline__ s8v fdup(s4v a) {
  return __builtin_shufflevector(a, a, 0,1,2,3,0,1,2,3);
}
__device__ __forceinline__ s8v fhl(s4v h, s4v l) {
  return __builtin_shufflevector(h, l, 0,1,2,3,4,5,6,7);
}
__device__ __forceinline__ s8v fh0(s4v h) {
  s4v z = {0,0,0,0};
  return __builtin_shufflevector(h, z, 0,1,2,3,4,5,6,7);
}
__device__ __forceinline__ f32x4 binit(float b) { return f32x4{b,b,b,b}; }

#define MFMA(a,b,c) __builtin_amdgcn_mfma_f32_16x16x32_bf16((a),(b),(c),0,0,0)

// act+store helpers: C layout row=4g+r, col=c
__device__ __forceinline__ void act_split_sp(f32x4 acc, int g, int c,
                                             short* ih, short* il) {
#pragma unroll
  for (int r = 0; r < 4; ++r) {
    float v = sp_stable(acc[r]);
    unsigned short h = b16hi(v);
    ih[(4*g + r)*STR + c] = (short)h;
    il[(4*g + r)*STR + c] = (short)b16hi(v - b16tof(h));
  }
}
__device__ __forceinline__ void act_one_sig(f32x4 acc, int g, int c, short* img) {
#pragma unroll
  for (int r = 0; r < 4; ++r)
    img[(4*g + r)*STR + c] = (short)b16hi(sigmoid_f(acc[r]));
}

__global__ __launch_bounds__(256, 2) void isnn_fwd(
    const float* __restrict__ x0g, const float* __restrict__ y0g,
    const float* __restrict__ z0g, const float* __restrict__ t0g,
    const unsigned int* __restrict__ Bbuf, const float* __restrict__ biasb,
    float* __restrict__ outg)
{
  __shared__ short imgs[4][8][16*STR];   // per-wave: X0,IN,Xhi,Xlo,Yhi,Ylo,Z,T

  const int lane = threadIdx.x & 63;
  const int w    = threadIdx.x >> 6;
  const int g    = lane >> 4;
  const int c    = lane & 15;

  short* X0  = &imgs[w][0][0];
  short* IN  = &imgs[w][1][0];
  short* Xhi = &imgs[w][2][0];
  short* Xlo = &imgs[w][3][0];
  short* Yhi = &imgs[w][4][0];
  short* Ylo = &imgs[w][5][0];
  short* Zm  = &imgs[w][6][0];
  short* Tm  = &imgs[w][7][0];

  // ---- B frags into registers (uniform across waves -> L2 broadcast)
  s8v Bm[NSLOT];
#pragma unroll
  for (int s = 0; s < NSLOT; ++s)
    Bm[s] = *(const s8v*)(Bbuf + s*256 + lane*4);

  float bias_v[NBIAS];
#pragma unroll
  for (int b = 0; b < NBIAS; ++b) bias_v[b] = biasb[b*16 + c];

  const int wgid = blockIdx.x * 4 + w;      // 0..16383
  const int T0   = wgid * 4;

  // input regs for current tile (prefetch pipeline)
  float4 Xr; float2 Yr, Zr; float Tr;
  {
    Xr = ((const float4*)x0g)[(size_t)T0*64 + lane];
    Yr = ((const float2*)y0g)[(size_t)T0*64 + lane];
    Zr = ((const float2*)z0g)[(size_t)T0*64 + lane];
    Tr = t0g[(size_t)T0*64 + lane];
  }

#pragma unroll
  for (int it = 0; it < 4; ++it) {
    const int T = T0 + it;
    // ---- stage inputs into LDS images
    {
      int row = lane >> 2, q = lane & 3;
      s4v xv = { (short)b16hi(Xr.x), (short)b16hi(Xr.y),
                 (short)b16hi(Xr.z), (short)b16hi(Xr.w) };
      *(s4v*)(X0 + row*STR + q*4) = xv;
      s2v yv = { (short)b16hi(Yr.x), (short)b16hi(Yr.y) };
      *(s2v*)(IN + row*STR + q*2) = yv;
      s2v zv = { (short)b16hi(Zr.x), (short)b16hi(Zr.y) };
      *(s2v*)(IN + row*STR + 8 + q*2) = zv;
      IN[row*STR + 16 + q] = (short)b16hi(Tr);
    }
    // ---- prefetch next tile's inputs (issue early, hide under compute)
    if (it < 3) {
      Xr = ((const float4*)x0g)[(size_t)(T+1)*64 + lane];
      Yr = ((const float2*)y0g)[(size_t)(T+1)*64 + lane];
      Zr = ((const float2*)z0g)[(size_t)(T+1)*64 + lane];
      Tr = t0g[(size_t)(T+1)*64 + lane];
    }

    // ---- towers layer 1
    s4v vy0 = rd4(IN, c, 4*(g & 1));
    s4v vz0 = rd4(IN, c, 8 + 4*(g & 1));
    s4v vt0 = rd4(IN, c, 16);
    f32x4 aY = binit(bias_v[0]);
    f32x4 aZ = binit(bias_v[4]);
    f32x4 aT = binit(bias_v[8]);
    aY = MFMA(fdup(vy0), Bm[0],  aY);
    aZ = MFMA(fdup(vz0), Bm[7],  aZ);
    aT = MFMA(fdup(vt0), Bm[11], aT);
    act_split_sp(aY, g, c, Yhi, Ylo);
    act_one_sig(aZ, g, c, Zm);
    act_one_sig(aT, g, c, Tm);

    // ---- towers layers 2..4
#pragma unroll
    for (int l2 = 0; l2 < 3; ++l2) {
      s4v yh = rd4(Yhi, c, 4*g), yl = rd4(Ylo, c, 4*g);
      s4v zf = rd4(Zm,  c, 4*g), tf = rd4(Tm,  c, 4*g);
      f32x4 nY = binit(bias_v[1 + l2]);
      nY = MFMA(fhl(yh, yl), Bm[1 + 2*l2], nY);
      nY = MFMA(fh0(yh),     Bm[2 + 2*l2], nY);
      f32x4 nZ = binit(bias_v[5 + l2]);
      nZ = MFMA(fdup(zf), Bm[8 + l2], nZ);
      f32x4 nT = binit(bias_v[9 + l2]);
      nT = MFMA(fdup(tf), Bm[12 + l2], nT);
      act_split_sp(nY, g, c, Yhi, Ylo);
      act_one_sig(nZ, g, c, Zm);
      act_one_sig(nT, g, c, Tm);
    }

    // ---- persistent frags for x path
    s4v Fyh = rd4(Yhi, c, 4*g), Fyl = rd4(Ylo, c, 4*g);
    s4v Fz  = rd4(Zm,  c, 4*g), Ft  = rd4(Tm,  c, 4*g);
    s4v Fx0 = rd4(X0,  c, 4*g);

    // ---- x first block
    f32x4 xA = binit(bias_v[12]);
    xA = MFMA(fdup(Fx0), Bm[15], xA);
    s4v vin = rd4(IN, c, 4*g);
    f32x4 xB = {0.f, 0.f, 0.f, 0.f};
    xB = MFMA(fdup(vin), Bm[16], xB);
    xB = MFMA(fdup(vt0), Bm[17], xB);
    act_split_sp(xA + xB, g, c, Xhi, Xlo);

    // ---- 3 x iterations
#pragma unroll
    for (int i = 0; i < 3; ++i) {
      s4v xh = rd4(Xhi, c, 4*g), xl = rd4(Xlo, c, 4*g);
      f32x4 A = binit(bias_v[13 + i]);
      A = MFMA(fhl(xh, xl),   Bm[18 + 7*i], A);
      A = MFMA(fh0(xh),       Bm[19 + 7*i], A);
      A = MFMA(fdup(Fx0),     Bm[20 + 7*i], A);
      f32x4 Bq = {0.f, 0.f, 0.f, 0.f};
      Bq = MFMA(fhl(Fyh, Fyl), Bm[21 + 7*i], Bq);
      Bq = MFMA(fh0(Fyh),      Bm[22 + 7*i], Bq);
      Bq = MFMA(fdup(Fz),      Bm[23 + 7*i], Bq);
      Bq = MFMA(fdup(Ft),      Bm[24 + 7*i], Bq);
      act_split_sp(A + Bq, g, c, Xhi, Xlo);
    }

    // ---- final linear + store
    {
      s4v xh = rd4(Xhi, c, 4*g), xl = rd4(Xlo, c, 4*g);
      f32x4 oA = binit(bias_v[16]);
      oA = MFMA(fhl(xh, xl), Bm[39], oA);
      f32x4 oB = {0.f, 0.f, 0.f, 0.f};
      oB = MFMA(fh0(xh), Bm[40], oB);
      f32x4 o = oA + oB;
      if (c < 15) {
        size_t base = ((size_t)T*16 + 4*g) * 15 + c;
#pragma unroll
        for (int r = 0; r < 4; ++r) outg[base + (size_t)r*15] = o[r];
      }
    }
  }
}

extern "C" void kernel_launch(void* const* d_in, const int* in_sizes, int n_in,
                              void* d_out, int out_size, void* d_ws, size_t ws_size,
                              hipStream_t stream) {
  const float* x0  = (const float*)d_in[0];
  const float* y0  = (const float*)d_in[1];
  const float* z0  = (const float*)d_in[2];
  const float* t0  = (const float*)d_in[3];
  const float* yW0 = (const float*)d_in[4];
  const float* yWs = (const float*)d_in[5];
  const float* yb  = (const float*)d_in[6];
  const float* zW0 = (const float*)d_in[7];
  const float* zWs = (const float*)d_in[8];
  const float* zb  = (const float*)d_in[9];
  const float* tW0 = (const float*)d_in[10];
  const float* tWs = (const float*)d_in[11];
  const float* tb  = (const float*)d_in[12];
  const float* x0W = (const float*)d_in[13];
  const float* x0b = (const float*)d_in[14];
  const float* y0W = (const float*)d_in[15];
  const float* y0b = (const float*)d_in[16];
  const float* z0W = (const float*)d_in[17];
  const float* z0b = (const float*)d_in[18];
  const float* t0W = (const float*)d_in[19];
  const float* t0b = (const float*)d_in[20];
  const float* xWs = (const float*)d_in[21];
  const float* xb  = (const float*)d_in[22];
  const float* xsW = (const float*)d_in[23];
  const float* xsb = (const float*)d_in[24];
  const float* xyW = (const float*)d_in[25];
  const float* xyb = (const float*)d_in[26];
  const float* xzW = (const float*)d_in[27];
  const float* xzb = (const float*)d_in[28];
  const float* xtW = (const float*)d_in[29];
  const float* xtb = (const float*)d_in[30];
  const float* fW  = (const float*)d_in[31];
  const float* fb  = (const float*)d_in[32];

  unsigned int* Bbuf = (unsigned int*)d_ws;
  float* biasb = (float*)(Bbuf + NSLOT*256);

  prep_kernel<<<16, 256, 0, stream>>>(yW0, yWs, yb, zW0, zWs, zb, tW0, tWs, tb,
                                      x0W, x0b, y0W, y0b, z0W, z0b, t0W, t0b,
                                      xWs, xb, xsW, xsb, xyW, xyb, xzW, xzb,
                                      xtW, xtb, fW, fb, Bbuf, biasb);

  const int n = in_sizes[0] / 16;          // N rows (1048576)
  const int blocks = n / 256;              // 4 waves x 4 tiles x 16 rows per block
  isnn_fwd<<<blocks, 256, 0, stream>>>(x0, y0, z0, t0, Bbuf, biasb, (float*)d_out);
}

// Round 6
// 156.237 us; speedup vs baseline: 1.9126x; 1.2727x over previous
//
#include <hip/hip_runtime.h>
#include <hip/hip_bf16.h>

typedef short s8v  __attribute__((ext_vector_type(8)));
typedef float f32x4 __attribute__((ext_vector_type(4)));
typedef unsigned int u32;
typedef u32 u32x4 __attribute__((ext_vector_type(4)));

#define NSLOT 31

// ---------- bf16 helpers (RNE) ----------
__device__ __forceinline__ unsigned short b16hi(float v) {
  unsigned int u = __float_as_uint(v);
  return (unsigned short)((u + 0x7FFFu + ((u >> 16) & 1u)) >> 16);
}
__device__ __forceinline__ float b16tof(unsigned short h) {
  return __uint_as_float(((unsigned int)h) << 16);
}
__device__ __forceinline__ unsigned short lobits(float w) {
  return b16hi(w - b16tof(b16hi(w)));
}
__device__ __forceinline__ float sp_stable(float v) {
  float ax = __builtin_fabsf(v);
  float e  = __expf(-ax);
  return fmaxf(v, 0.0f) + __logf(1.0f + e);
}
__device__ __forceinline__ float sigmoid_f(float v) {
  return __builtin_amdgcn_rcpf(1.0f + __expf(-v));
}

// =====================================================================
// PREP: A-operand fragments for D = W . act^T   (m = out-channel j, k = in)
// lane l: m = l&15, k = 4*(l>>4)+{0..3} (dw0,1) and 16+4*(l>>4)+{0..3} (dw2,3),
// low 16 bits of each dword = even k.  Biases injected at spare k slots; the
// runtime B-frags carry bf16 1.0 at the matching k.
// Slots:
//  0: yW0(sp) k0..7 hi, k8..15 lo, k16/17 = yb0 hi/lo
//  1..3: yWs[i](sp) 15-in + yb[i+1] @ k15/k31
//  4: zW0 k0..7 hi, k8..15 lo, k16/17 zb0
//  5..7: zWs[i] + zb[i+1]
//  8: tW0(sp) k0..3 hi, k4..7 lo, k8/9 tb0
//  9..11: tWs[i](sp) + tb[i+1]
//  12: x0W k0..15 hi, k16..31 lo (no bias)
//  13: y0W(sp) k0..7 hi | z0W k8..15 hi | y0W lo k16..23 | z0W lo k24..31
//  14: t0W(sp) k0..3 hi, k4..7 lo, k8/9 = xfb (x0b+y0b+z0b+t0b)
//  15+5i: xWs[i](sp) 15-in + xlb[i] @ k15/k31
//  16+5i: xsW[i] 16-in
//  17+5i: xyW[i](sp) 15-in NO bias (k15=k31=0)
//  18+5i: xzW[i] 15-in no bias
//  19+5i: xtW[i](sp) 15-in no bias
//  30: fW 15-in + fb @ k15/k31
// =====================================================================
struct P {
  const float *yW0,*yWs,*yb,*zW0,*zWs,*zb,*tW0,*tWs,*tb;
  const float *x0W,*x0b,*y0W,*y0b,*z0W,*z0b,*t0W,*t0b;
  const float *xWs,*xb,*xsW,*xsb,*xyW,*xyb,*xzW,*xzb,*xtW,*xtb,*fW,*fb;
};

// 15-input slot with optional softplus and optional bias
__device__ unsigned short pat15(const float* W, const float* b, int k, int j, int sp) {
  if (k < 15)  { float v = W[j*15+k];      return b16hi(sp ? sp_stable(v) : v); }
  if (k == 15) return b ? b16hi(b[j]) : (unsigned short)0;
  if (k < 31)  { float v = W[j*15+(k-16)]; return lobits(sp ? sp_stable(v) : v); }
  return b ? lobits(b[j]) : (unsigned short)0;
}

__device__ unsigned short wA(int s, int k, int j, const P& p) {
  if (j > 14) return 0;
  if (s == 0) {
    if (k < 8)   return b16hi(sp_stable(p.yW0[j*8+k]));
    if (k < 16)  return lobits(sp_stable(p.yW0[j*8+(k-8)]));
    if (k == 16) return b16hi(p.yb[j]);
    if (k == 17) return lobits(p.yb[j]);
    return 0;
  }
  if (s <= 3)  return pat15(p.yWs + (s-1)*225, p.yb + s*15, k, j, 1);
  if (s == 4) {
    if (k < 8)   return b16hi(p.zW0[j*8+k]);
    if (k < 16)  return lobits(p.zW0[j*8+(k-8)]);
    if (k == 16) return b16hi(p.zb[j]);
    if (k == 17) return lobits(p.zb[j]);
    return 0;
  }
  if (s <= 7)  return pat15(p.zWs + (s-5)*225, p.zb + (s-4)*15, k, j, 0);
  if (s == 8) {
    if (k < 4)   return b16hi(sp_stable(p.tW0[j*4+k]));
    if (k < 8)   return lobits(sp_stable(p.tW0[j*4+(k-4)]));
    if (k == 8)  return b16hi(p.tb[j]);
    if (k == 9)  return lobits(p.tb[j]);
    return 0;
  }
  if (s <= 11) return pat15(p.tWs + (s-9)*225, p.tb + (s-8)*15, k, j, 1);
  if (s == 12) {
    if (k < 16) return b16hi(p.x0W[j*16+k]);
    return lobits(p.x0W[j*16+(k-16)]);
  }
  if (s == 13) {
    if (k < 8)  return b16hi(sp_stable(p.y0W[j*8+k]));
    if (k < 16) return b16hi(p.z0W[j*8+(k-8)]);
    if (k < 24) return lobits(sp_stable(p.y0W[j*8+(k-16)]));
    return lobits(p.z0W[j*8+(k-24)]);
  }
  if (s == 14) {
    if (k < 4)  return b16hi(sp_stable(p.t0W[j*4+k]));
    if (k < 8)  return lobits(sp_stable(p.t0W[j*4+(k-4)]));
    float xfb = p.x0b[j] + p.y0b[j] + p.z0b[j] + p.t0b[j];
    if (k == 8) return b16hi(xfb);
    if (k == 9) return lobits(xfb);
    return 0;
  }
  if (s <= 29) {
    int i = (s-15)/5, r = (s-15)%5;
    if (r == 0) {
      if (k == 15 || k == 31) {
        float xlb = p.xb[i*15+j] + p.xsb[i*15+j] + p.xyb[i*15+j]
                  + p.xzb[i*15+j] + p.xtb[i*15+j];
        return (k == 15) ? b16hi(xlb) : lobits(xlb);
      }
      return pat15(p.xWs + i*225, nullptr, k, j, 1);
    }
    if (r == 1) {
      const float* W = p.xsW + i*240;
      if (k < 16) return b16hi(W[j*16+k]);
      return lobits(W[j*16+(k-16)]);
    }
    if (r == 2) return pat15(p.xyW + i*225, nullptr, k, j, 1);
    if (r == 3) return pat15(p.xzW + i*225, nullptr, k, j, 0);
    return pat15(p.xtW + i*225, nullptr, k, j, 1);
  }
  return pat15(p.fW, p.fb, k, j, 0);   // s == 30
}

__global__ void prep_kernel(P p, u32* Abuf) {
  const int tid = blockIdx.x * blockDim.x + threadIdx.x;
  const int str = gridDim.x * blockDim.x;
  for (int idx = tid; idx < NSLOT*256; idx += str) {
    int s = idx >> 8, rem = idx & 255, l = rem >> 2, d = rem & 3;
    int g = l >> 4, j = l & 15;
    int kb = (d < 2) ? (4*g + 2*d) : (16 + 4*g + 2*(d-2));
    u32 v0 = wA(s, kb,   j, p);
    u32 v1 = wA(s, kb+1, j, p);
    Abuf[idx] = v0 | (v1 << 16);
  }
}

// =====================================================================
// MAIN: layer chain entirely in registers (swapped-operand MFMA).
// =====================================================================
union FragU { u32x4 u; s8v s; };
__device__ __forceinline__ s8v mkfrag(u32 a, u32 b, u32 c, u32 d) {
  FragU f; f.u = u32x4{a, b, c, d}; return f.s;
}
__device__ __forceinline__ u32 pk(float lo, float hi) {
  union { __hip_bfloat162 h; u32 u; } cv;
  cv.h = __float22bfloat162_rn(float2{lo, hi});
  return cv.u;
}
__device__ __forceinline__ float lo16f(u32 u) { return __uint_as_float(u << 16); }
__device__ __forceinline__ float hi16f(u32 u) { return __uint_as_float(u & 0xFFFF0000u); }

#define MFMA(A,B,C) __builtin_amdgcn_mfma_f32_16x16x32_bf16((A),(B),(C),0,0,0)
#define ONE2 0x3F803F80u

// softplus act -> hi frag dwords (k15 -> 1.0 for bias) + lo frag dwords (k15 -> 0)
__device__ __forceinline__ void act_sp(f32x4 a, int g,
                                       u32& h0, u32& h1, u32& l0, u32& l1) {
  float v0 = sp_stable(a[0]), v1 = sp_stable(a[1]);
  float v2 = sp_stable(a[2]), v3 = sp_stable(a[3]);
  h0 = pk(v0, v1);
  u32 h1u = pk(v2, v3);
  l0 = pk(v0 - lo16f(h0),  v1 - hi16f(h0));
  l1 = pk(v2 - lo16f(h1u), v3 - hi16f(h1u));
  h1 = (g == 3) ? ((h1u & 0xFFFFu) | 0x3F800000u) : h1u;
  l1 = (g == 3) ? (l1 & 0xFFFFu) : l1;
}
// sigmoid act -> single-bf16 frag dwords (k15 -> 1.0)
__device__ __forceinline__ void act_sig(f32x4 a, int g, u32& d0, u32& d1) {
  d0 = pk(sigmoid_f(a[0]), sigmoid_f(a[1]));
  u32 d1u = pk(sigmoid_f(a[2]), sigmoid_f(a[3]));
  d1 = (g == 3) ? ((d1u & 0xFFFFu) | 0x3F800000u) : d1u;
}

__global__ __launch_bounds__(256, 2) void isnn_fwd(
    const float* __restrict__ x0g, const float* __restrict__ y0g,
    const float* __restrict__ z0g, const float* __restrict__ t0g,
    const u32* __restrict__ Abuf, float* __restrict__ outg)
{
  __shared__ float olds[4][320];          // per-wave out staging, stride 20

  const int lane = threadIdx.x & 63;
  const int w    = threadIdx.x >> 6;
  const int g    = lane >> 4;
  const int c    = lane & 15;

  // ---- weight A-frags: loaded once, stay in VGPRs (static indices only)
  FragU Aw[NSLOT];
#pragma unroll
  for (int s = 0; s < NSLOT; ++s)
    Aw[s].u = ((const u32x4*)Abuf)[s*64 + lane];

  // ---- coalesced-output index precompute
  int oidx[4]; bool oon[4];
#pragma unroll
  for (int jj = 0; jj < 4; ++jj) {
    int i = lane + 64*jj;
    oon[jj]  = (i < 240);
    int row  = i / 15, ch = i - row*15;
    oidx[jj] = row*20 + ch;
  }

  const int T0 = (blockIdx.x * 4 + w) * 4;
  const f32x4 zero4 = {0.f, 0.f, 0.f, 0.f};

  // ---- input regs (tile prefetch pipeline); lane (g,c) reads row c
  float4 x4 = ((const float4*)x0g)[(size_t)(T0*16 + c)*4 + g];
  float4 y4 = ((const float4*)y0g)[(size_t)(T0*16 + c)*2 + (g & 1)];
  float4 z4 = ((const float4*)z0g)[(size_t)(T0*16 + c)*2 + (g & 1)];
  float4 t4 = ((const float4*)t0g)[(size_t)(T0*16 + c)];

#pragma unroll
  for (int it = 0; it < 4; ++it) {
    const int T = T0 + it;

    // ---- build input B-frags (single-bf16 inputs, same as R5)
    u32 dx0 = pk(x4.x, x4.y), dx1 = pk(x4.z, x4.w);
    u32 dy0 = pk(y4.x, y4.y), dy1 = pk(y4.z, y4.w);
    u32 dz0 = pk(z4.x, z4.y), dz1 = pk(z4.z, z4.w);
    u32 dt0 = pk(t4.x, t4.y), dt1 = pk(t4.z, t4.w);
    s8v Bx0 = mkfrag(dx0, dx1, dx0, dx1);
    s8v By0 = mkfrag(dy0, dy1, (g == 0) ? ONE2 : 0u, 0u);
    s8v Bz0 = mkfrag(dz0, dz1, (g == 0) ? ONE2 : 0u, 0u);
    s8v Bt0 = mkfrag((g < 2) ? dt0 : ((g == 2) ? ONE2 : 0u),
                     (g < 2) ? dt1 : 0u, 0u, 0u);
    u32 syz0 = (g < 2) ? dy0 : dz0, syz1 = (g < 2) ? dy1 : dz1;
    s8v Byz = mkfrag(syz0, syz1, syz0, syz1);

    // ---- prefetch next tile's inputs (hidden under this tile's compute)
    if (it < 3) {
      x4 = ((const float4*)x0g)[(size_t)((T+1)*16 + c)*4 + g];
      y4 = ((const float4*)y0g)[(size_t)((T+1)*16 + c)*2 + (g & 1)];
      z4 = ((const float4*)z0g)[(size_t)((T+1)*16 + c)*2 + (g & 1)];
      t4 = ((const float4*)t0g)[(size_t)((T+1)*16 + c)];
    }

    // ---- towers layer 1 (bias via k16/17 or k8/9 slots)
    f32x4 aY = MFMA(Aw[0].s, By0, zero4);
    f32x4 aZ = MFMA(Aw[4].s, Bz0, zero4);
    f32x4 aT = MFMA(Aw[8].s, Bt0, zero4);

    // ---- towers layers 2..4 (all chaining in-register)
    u32 yh0, yh1, yl0, yl1, zf0, zf1, tf0, tf1;
#pragma unroll
    for (int l = 0; l < 3; ++l) {
      act_sp(aY, g, yh0, yh1, yl0, yl1);
      act_sig(aZ, g, zf0, zf1);
      act_sig(aT, g, tf0, tf1);
      aY = MFMA(Aw[1+l].s, mkfrag(yh0, yh1, yh0, yh1), zero4);
      aY = MFMA(Aw[1+l].s, mkfrag(yl0, yl1, 0u, 0u), aY);
      aZ = MFMA(Aw[5+l].s, mkfrag(zf0, zf1, zf0, zf1), zero4);
      aT = MFMA(Aw[9+l].s, mkfrag(tf0, tf1, tf0, tf1), zero4);
    }
    // final tower activations (persist through x path)
    act_sp(aY, g, yh0, yh1, yl0, yl1);
    act_sig(aZ, g, zf0, zf1);
    act_sig(aT, g, tf0, tf1);
    s8v FyH = mkfrag(yh0, yh1, yh0, yh1);
    s8v FyL = mkfrag(yl0, yl1, 0u, 0u);
    s8v Fz  = mkfrag(zf0, zf1, zf0, zf1);
    s8v Ft  = mkfrag(tf0, tf1, tf0, tf1);

    // ---- x first block (bias xfb via Bt0 k8/9 against slot 14)
    f32x4 aX = MFMA(Aw[12].s, Bx0, zero4);
    aX = MFMA(Aw[13].s, Byz, aX);
    aX = MFMA(Aw[14].s, Bt0, aX);

    // ---- 3 x iterations
    u32 xh0, xh1, xl0, xl1;
#pragma unroll
    for (int i = 0; i < 3; ++i) {
      act_sp(aX, g, xh0, xh1, xl0, xl1);
      aX = MFMA(Aw[15+5*i].s, mkfrag(xh0, xh1, xh0, xh1), zero4);
      aX = MFMA(Aw[15+5*i].s, mkfrag(xl0, xl1, 0u, 0u), aX);
      aX = MFMA(Aw[16+5*i].s, Bx0, aX);
      aX = MFMA(Aw[17+5*i].s, FyH, aX);
      aX = MFMA(Aw[17+5*i].s, FyL, aX);
      aX = MFMA(Aw[18+5*i].s, Fz, aX);
      aX = MFMA(Aw[19+5*i].s, Ft, aX);
    }

    // ---- final linear
    act_sp(aX, g, xh0, xh1, xl0, xl1);
    f32x4 aO = MFMA(Aw[30].s, mkfrag(xh0, xh1, xh0, xh1), zero4);
    aO = MFMA(Aw[30].s, mkfrag(xl0, xl1, 0u, 0u), aO);

    // ---- coalesced store via tiny LDS transpose (chan 15 slot is dead pad)
    *(f32x4*)(&olds[w][c*20 + 4*g]) = aO;
    float* orow = outg + (size_t)T * 240;
#pragma unroll
    for (int jj = 0; jj < 4; ++jj)
      if (oon[jj]) orow[lane + 64*jj] = olds[w][oidx[jj]];
  }
}

extern "C" void kernel_launch(void* const* d_in, const int* in_sizes, int n_in,
                              void* d_out, int out_size, void* d_ws, size_t ws_size,
                              hipStream_t stream) {
  P p;
  p.yW0 = (const float*)d_in[4];  p.yWs = (const float*)d_in[5];  p.yb  = (const float*)d_in[6];
  p.zW0 = (const float*)d_in[7];  p.zWs = (const float*)d_in[8];  p.zb  = (const float*)d_in[9];
  p.tW0 = (const float*)d_in[10]; p.tWs = (const float*)d_in[11]; p.tb  = (const float*)d_in[12];
  p.x0W = (const float*)d_in[13]; p.x0b = (const float*)d_in[14];
  p.y0W = (const float*)d_in[15]; p.y0b = (const float*)d_in[16];
  p.z0W = (const float*)d_in[17]; p.z0b = (const float*)d_in[18];
  p.t0W = (const float*)d_in[19]; p.t0b = (const float*)d_in[20];
  p.xWs = (const float*)d_in[21]; p.xb  = (const float*)d_in[22];
  p.xsW = (const float*)d_in[23]; p.xsb = (const float*)d_in[24];
  p.xyW = (const float*)d_in[25]; p.xyb = (const float*)d_in[26];
  p.xzW = (const float*)d_in[27]; p.xzb = (const float*)d_in[28];
  p.xtW = (const float*)d_in[29]; p.xtb = (const float*)d_in[30];
  p.fW  = (const float*)d_in[31]; p.fb  = (const float*)d_in[32];

  u32* Abuf = (u32*)d_ws;
  prep_kernel<<<8, 256, 0, stream>>>(p, Abuf);

  const float* x0 = (const float*)d_in[0];
  const float* y0 = (const float*)d_in[1];
  const float* z0 = (const float*)d_in[2];
  const float* t0 = (const float*)d_in[3];

  const int n = in_sizes[0] / 16;          // 1048576 rows
  const int blocks = n / 256;              // 4 waves x 4 tiles x 16 rows
  isnn_fwd<<<blocks, 256, 0, stream>>>(x0, y0, z0, t0, Abuf, (float*)d_out);
}

// Round 7
// 151.679 us; speedup vs baseline: 1.9701x; 1.0300x over previous
//
#include <hip/hip_runtime.h>
#include <hip/hip_bf16.h>

typedef short s8v  __attribute__((ext_vector_type(8)));
typedef float f32x4 __attribute__((ext_vector_type(4)));
typedef unsigned int u32;
typedef u32 u32x4 __attribute__((ext_vector_type(4)));

#define NSLOT 31

// ---------- bf16 helpers (RNE) ----------
__device__ __forceinline__ unsigned short b16hi(float v) {
  unsigned int u = __float_as_uint(v);
  return (unsigned short)((u + 0x7FFFu + ((u >> 16) & 1u)) >> 16);
}
__device__ __forceinline__ float b16tof(unsigned short h) {
  return __uint_as_float(((unsigned int)h) << 16);
}
__device__ __forceinline__ unsigned short lobits(float w) {
  return b16hi(w - b16tof(b16hi(w)));
}
__device__ __forceinline__ float sp_stable(float v) {
  float ax = __builtin_fabsf(v);
  float e  = __expf(-ax);
  return fmaxf(v, 0.0f) + __logf(1.0f + e);
}
__device__ __forceinline__ float sigmoid_f(float v) {
  return __builtin_amdgcn_rcpf(1.0f + __expf(-v));
}

// =====================================================================
// PREP (identical to R6, verified): A-frags for D = W . act^T
// lane l: m = l&15, k = 4*(l>>4)+{0..3} (dw0,1) and 16+4*(l>>4)+{0..3} (dw2,3)
// =====================================================================
struct P {
  const float *yW0,*yWs,*yb,*zW0,*zWs,*zb,*tW0,*tWs,*tb;
  const float *x0W,*x0b,*y0W,*y0b,*z0W,*z0b,*t0W,*t0b;
  const float *xWs,*xb,*xsW,*xsb,*xyW,*xyb,*xzW,*xzb,*xtW,*xtb,*fW,*fb;
};

__device__ unsigned short pat15(const float* W, const float* b, int k, int j, int sp) {
  if (k < 15)  { float v = W[j*15+k];      return b16hi(sp ? sp_stable(v) : v); }
  if (k == 15) return b ? b16hi(b[j]) : (unsigned short)0;
  if (k < 31)  { float v = W[j*15+(k-16)]; return lobits(sp ? sp_stable(v) : v); }
  return b ? lobits(b[j]) : (unsigned short)0;
}

__device__ unsigned short wA(int s, int k, int j, const P& p) {
  if (j > 14) return 0;
  if (s == 0) {
    if (k < 8)   return b16hi(sp_stable(p.yW0[j*8+k]));
    if (k < 16)  return lobits(sp_stable(p.yW0[j*8+(k-8)]));
    if (k == 16) return b16hi(p.yb[j]);
    if (k == 17) return lobits(p.yb[j]);
    return 0;
  }
  if (s <= 3)  return pat15(p.yWs + (s-1)*225, p.yb + s*15, k, j, 1);
  if (s == 4) {
    if (k < 8)   return b16hi(p.zW0[j*8+k]);
    if (k < 16)  return lobits(p.zW0[j*8+(k-8)]);
    if (k == 16) return b16hi(p.zb[j]);
    if (k == 17) return lobits(p.zb[j]);
    return 0;
  }
  if (s <= 7)  return pat15(p.zWs + (s-5)*225, p.zb + (s-4)*15, k, j, 0);
  if (s == 8) {
    if (k < 4)   return b16hi(sp_stable(p.tW0[j*4+k]));
    if (k < 8)   return lobits(sp_stable(p.tW0[j*4+(k-4)]));
    if (k == 8)  return b16hi(p.tb[j]);
    if (k == 9)  return lobits(p.tb[j]);
    return 0;
  }
  if (s <= 11) return pat15(p.tWs + (s-9)*225, p.tb + (s-8)*15, k, j, 1);
  if (s == 12) {
    if (k < 16) return b16hi(p.x0W[j*16+k]);
    return lobits(p.x0W[j*16+(k-16)]);
  }
  if (s == 13) {
    if (k < 8)  return b16hi(sp_stable(p.y0W[j*8+k]));
    if (k < 16) return b16hi(p.z0W[j*8+(k-8)]);
    if (k < 24) return lobits(sp_stable(p.y0W[j*8+(k-16)]));
    return lobits(p.z0W[j*8+(k-24)]);
  }
  if (s == 14) {
    if (k < 4)  return b16hi(sp_stable(p.t0W[j*4+k]));
    if (k < 8)  return lobits(sp_stable(p.t0W[j*4+(k-4)]));
    float xfb = p.x0b[j] + p.y0b[j] + p.z0b[j] + p.t0b[j];
    if (k == 8) return b16hi(xfb);
    if (k == 9) return lobits(xfb);
    return 0;
  }
  if (s <= 29) {
    int i = (s-15)/5, r = (s-15)%5;
    if (r == 0) {
      if (k == 15 || k == 31) {
        float xlb = p.xb[i*15+j] + p.xsb[i*15+j] + p.xyb[i*15+j]
                  + p.xzb[i*15+j] + p.xtb[i*15+j];
        return (k == 15) ? b16hi(xlb) : lobits(xlb);
      }
      return pat15(p.xWs + i*225, nullptr, k, j, 1);
    }
    if (r == 1) {
      const float* W = p.xsW + i*240;
      if (k < 16) return b16hi(W[j*16+k]);
      return lobits(W[j*16+(k-16)]);
    }
    if (r == 2) return pat15(p.xyW + i*225, nullptr, k, j, 1);
    if (r == 3) return pat15(p.xzW + i*225, nullptr, k, j, 0);
    return pat15(p.xtW + i*225, nullptr, k, j, 1);
  }
  return pat15(p.fW, p.fb, k, j, 0);   // s == 30
}

__global__ void prep_kernel(P p, u32* Abuf) {
  const int tid = blockIdx.x * blockDim.x + threadIdx.x;
  const int str = gridDim.x * blockDim.x;
  for (int idx = tid; idx < NSLOT*256; idx += str) {
    int s = idx >> 8, rem = idx & 255, l = rem >> 2, d = rem & 3;
    int g = l >> 4, j = l & 15;
    int kb = (d < 2) ? (4*g + 2*d) : (16 + 4*g + 2*(d-2));
    u32 v0 = wA(s, kb,   j, p);
    u32 v1 = wA(s, kb+1, j, p);
    Abuf[idx] = v0 | (v1 << 16);
  }
}

// =====================================================================
// MAIN: two tiles per wave in LOCKSTEP (intra-wave ILP fills MFMA/trans
// latency). Numerics identical to R6.
// =====================================================================
union FragU { u32x4 u; s8v s; };
__device__ __forceinline__ s8v mkfrag(u32 a, u32 b, u32 c, u32 d) {
  FragU f; f.u = u32x4{a, b, c, d}; return f.s;
}
__device__ __forceinline__ u32 pk(float lo, float hi) {
  union { __hip_bfloat162 h; u32 u; } cv;
  cv.h = __float22bfloat162_rn(float2{lo, hi});
  return cv.u;
}
__device__ __forceinline__ float lo16f(u32 u) { return __uint_as_float(u << 16); }
__device__ __forceinline__ float hi16f(u32 u) { return __uint_as_float(u & 0xFFFF0000u); }

#define MFMA(A,B,C) __builtin_amdgcn_mfma_f32_16x16x32_bf16((A),(B),(C),0,0,0)
#define ONE2 0x3F803F80u

__device__ __forceinline__ void act_sp(f32x4 a, int g,
                                       u32& h0, u32& h1, u32& l0, u32& l1) {
  float v0 = sp_stable(a[0]), v1 = sp_stable(a[1]);
  float v2 = sp_stable(a[2]), v3 = sp_stable(a[3]);
  h0 = pk(v0, v1);
  u32 h1u = pk(v2, v3);
  l0 = pk(v0 - lo16f(h0),  v1 - hi16f(h0));
  l1 = pk(v2 - lo16f(h1u), v3 - hi16f(h1u));
  h1 = (g == 3) ? ((h1u & 0xFFFFu) | 0x3F800000u) : h1u;
  l1 = (g == 3) ? (l1 & 0xFFFFu) : l1;
}
__device__ __forceinline__ void act_sig(f32x4 a, int g, u32& d0, u32& d1) {
  d0 = pk(sigmoid_f(a[0]), sigmoid_f(a[1]));
  u32 d1u = pk(sigmoid_f(a[2]), sigmoid_f(a[3]));
  d1 = (g == 3) ? ((d1u & 0xFFFFu) | 0x3F800000u) : d1u;
}

#define LOAD_IN(T, vx, vy, vz, vt)                                         \
  vx = ((const float4*)x0g)[(size_t)((T)*16 + c)*4 + g];                   \
  vy = ((const float4*)y0g)[(size_t)((T)*16 + c)*2 + (g & 1)];             \
  vz = ((const float4*)z0g)[(size_t)((T)*16 + c)*2 + (g & 1)];             \
  vt = ((const float4*)t0g)[(size_t)((T)*16 + c)];

// One PAIR of tiles (TIA, TIB = TIA+1), fully interleaved A/B statements.
#define PAIR(TIA, vxA,vyA,vzA,vtA, vxB,vyB,vzB,vtB, PREF) {                \
  u32 pxA0=pk(vxA.x,vxA.y), pxA1=pk(vxA.z,vxA.w);                          \
  u32 pxB0=pk(vxB.x,vxB.y), pxB1=pk(vxB.z,vxB.w);                          \
  u32 pyA0=pk(vyA.x,vyA.y), pyA1=pk(vyA.z,vyA.w);                          \
  u32 pyB0=pk(vyB.x,vyB.y), pyB1=pk(vyB.z,vyB.w);                          \
  u32 pzA0=pk(vzA.x,vzA.y), pzA1=pk(vzA.z,vzA.w);                          \
  u32 pzB0=pk(vzB.x,vzB.y), pzB1=pk(vzB.z,vzB.w);                          \
  u32 ptA0=pk(vtA.x,vtA.y), ptA1=pk(vtA.z,vtA.w);                          \
  u32 ptB0=pk(vtB.x,vtB.y), ptB1=pk(vtB.z,vtB.w);                          \
  u32 bsl = (g == 0) ? ONE2 : 0u;                                          \
  s8v BxA = mkfrag(pxA0,pxA1,pxA0,pxA1), BxB = mkfrag(pxB0,pxB1,pxB0,pxB1);\
  s8v ByA = mkfrag(pyA0,pyA1,bsl,0u),    ByB = mkfrag(pyB0,pyB1,bsl,0u);   \
  s8v BzA = mkfrag(pzA0,pzA1,bsl,0u),    BzB = mkfrag(pzB0,pzB1,bsl,0u);   \
  s8v BtA = mkfrag((g<2)?ptA0:((g==2)?ONE2:0u), (g<2)?ptA1:0u, 0u, 0u);    \
  s8v BtB = mkfrag((g<2)?ptB0:((g==2)?ONE2:0u), (g<2)?ptB1:0u, 0u, 0u);    \
  u32 syA0=(g<2)?pyA0:pzA0, syA1=(g<2)?pyA1:pzA1;                          \
  u32 syB0=(g<2)?pyB0:pzB0, syB1=(g<2)?pyB1:pzB1;                          \
  s8v ByzA = mkfrag(syA0,syA1,syA0,syA1), ByzB = mkfrag(syB0,syB1,syB0,syB1);\
  PREF                                                                     \
  f32x4 aYA = MFMA(Aw[0].s, ByA, zero4), aYB = MFMA(Aw[0].s, ByB, zero4);  \
  f32x4 aZA = MFMA(Aw[4].s, BzA, zero4), aZB = MFMA(Aw[4].s, BzB, zero4);  \
  f32x4 aTA = MFMA(Aw[8].s, BtA, zero4), aTB = MFMA(Aw[8].s, BtB, zero4);  \
  u32 h0A,h1A,l0A,l1A, h0B,h1B,l0B,l1B;                                    \
  u32 sf0A,sf1A,sf0B,sf1B, uf0A,uf1A,uf0B,uf1B;                            \
  _Pragma("unroll")                                                        \
  for (int l = 0; l < 3; ++l) {                                            \
    act_sp(aYA,g,h0A,h1A,l0A,l1A);  act_sp(aYB,g,h0B,h1B,l0B,l1B);         \
    act_sig(aZA,g,sf0A,sf1A);       act_sig(aZB,g,sf0B,sf1B);              \
    act_sig(aTA,g,uf0A,uf1A);       act_sig(aTB,g,uf0B,uf1B);              \
    aYA = MFMA(Aw[1+l].s, mkfrag(h0A,h1A,h0A,h1A), zero4);                 \
    aYB = MFMA(Aw[1+l].s, mkfrag(h0B,h1B,h0B,h1B), zero4);                 \
    aYA = MFMA(Aw[1+l].s, mkfrag(l0A,l1A,0u,0u), aYA);                     \
    aYB = MFMA(Aw[1+l].s, mkfrag(l0B,l1B,0u,0u), aYB);                     \
    aZA = MFMA(Aw[5+l].s, mkfrag(sf0A,sf1A,sf0A,sf1A), zero4);             \
    aZB = MFMA(Aw[5+l].s, mkfrag(sf0B,sf1B,sf0B,sf1B), zero4);             \
    aTA = MFMA(Aw[9+l].s, mkfrag(uf0A,uf1A,uf0A,uf1A), zero4);             \
    aTB = MFMA(Aw[9+l].s, mkfrag(uf0B,uf1B,uf0B,uf1B), zero4);             \
  }                                                                        \
  act_sp(aYA,g,h0A,h1A,l0A,l1A);  act_sp(aYB,g,h0B,h1B,l0B,l1B);           \
  act_sig(aZA,g,sf0A,sf1A);       act_sig(aZB,g,sf0B,sf1B);                \
  act_sig(aTA,g,uf0A,uf1A);       act_sig(aTB,g,uf0B,uf1B);                \
  s8v FyHA = mkfrag(h0A,h1A,h0A,h1A), FyLA = mkfrag(l0A,l1A,0u,0u);        \
  s8v FyHB = mkfrag(h0B,h1B,h0B,h1B), FyLB = mkfrag(l0B,l1B,0u,0u);        \
  s8v FzA  = mkfrag(sf0A,sf1A,sf0A,sf1A), FzB = mkfrag(sf0B,sf1B,sf0B,sf1B);\
  s8v FtA  = mkfrag(uf0A,uf1A,uf0A,uf1A), FtB = mkfrag(uf0B,uf1B,uf0B,uf1B);\
  f32x4 aXA = MFMA(Aw[12].s, BxA, zero4), aXB = MFMA(Aw[12].s, BxB, zero4);\
  aXA = MFMA(Aw[13].s, ByzA, aXA);  aXB = MFMA(Aw[13].s, ByzB, aXB);       \
  aXA = MFMA(Aw[14].s, BtA,  aXA);  aXB = MFMA(Aw[14].s, BtB,  aXB);       \
  _Pragma("unroll")                                                        \
  for (int i = 0; i < 3; ++i) {                                            \
    act_sp(aXA,g,h0A,h1A,l0A,l1A);  act_sp(aXB,g,h0B,h1B,l0B,l1B);         \
    aXA = MFMA(Aw[15+5*i].s, mkfrag(h0A,h1A,h0A,h1A), zero4);              \
    aXB = MFMA(Aw[15+5*i].s, mkfrag(h0B,h1B,h0B,h1B), zero4);              \
    aXA = MFMA(Aw[15+5*i].s, mkfrag(l0A,l1A,0u,0u), aXA);                  \
    aXB = MFMA(Aw[15+5*i].s, mkfrag(l0B,l1B,0u,0u), aXB);                  \
    aXA = MFMA(Aw[16+5*i].s, BxA,  aXA);  aXB = MFMA(Aw[16+5*i].s, BxB,  aXB);\
    aXA = MFMA(Aw[17+5*i].s, FyHA, aXA);  aXB = MFMA(Aw[17+5*i].s, FyHB, aXB);\
    aXA = MFMA(Aw[17+5*i].s, FyLA, aXA);  aXB = MFMA(Aw[17+5*i].s, FyLB, aXB);\
    aXA = MFMA(Aw[18+5*i].s, FzA,  aXA);  aXB = MFMA(Aw[18+5*i].s, FzB,  aXB);\
    aXA = MFMA(Aw[19+5*i].s, FtA,  aXA);  aXB = MFMA(Aw[19+5*i].s, FtB,  aXB);\
  }                                                                        \
  act_sp(aXA,g,h0A,h1A,l0A,l1A);  act_sp(aXB,g,h0B,h1B,l0B,l1B);           \
  f32x4 aOA = MFMA(Aw[30].s, mkfrag(h0A,h1A,h0A,h1A), zero4);              \
  f32x4 aOB = MFMA(Aw[30].s, mkfrag(h0B,h1B,h0B,h1B), zero4);              \
  aOA = MFMA(Aw[30].s, mkfrag(l0A,l1A,0u,0u), aOA);                        \
  aOB = MFMA(Aw[30].s, mkfrag(l0B,l1B,0u,0u), aOB);                        \
  *(f32x4*)(obase +       c*20 + 4*g) = aOA;                               \
  *(f32x4*)(obase + 320 + c*20 + 4*g) = aOB;                               \
  float* orow = outg + (size_t)(TIA) * 240;                                \
  _Pragma("unroll")                                                        \
  for (int jj = 0; jj < 8; ++jj) {                                         \
    int ii = lane + 64*jj;                                                 \
    if (ii < 480) orow[ii] = obase[oidx[jj]];                              \
  }                                                                        \
}

__global__ __launch_bounds__(256, 2) void isnn_fwd(
    const float* __restrict__ x0g, const float* __restrict__ y0g,
    const float* __restrict__ z0g, const float* __restrict__ t0g,
    const u32* __restrict__ Abuf, float* __restrict__ outg)
{
  __shared__ float olds[4][2][320];        // per-wave staging for tile pair

  const int lane = threadIdx.x & 63;
  const int w    = threadIdx.x >> 6;
  const int g    = lane >> 4;
  const int c    = lane & 15;
  float* obase   = &olds[w][0][0];

  // ---- weight A-frags: resident in (unified) registers
  FragU Aw[NSLOT];
#pragma unroll
  for (int s = 0; s < NSLOT; ++s)
    Aw[s].u = ((const u32x4*)Abuf)[s*64 + lane];

  // ---- coalesced-store index precompute (480 floats = 2 tiles)
  int oidx[8];
#pragma unroll
  for (int jj = 0; jj < 8; ++jj) {
    int i   = lane + 64*jj;
    int u   = (i >= 240) ? 1 : 0;
    int rem = i - u*240;
    int row = rem / 15, ch = rem - row*15;
    oidx[jj] = u*320 + row*20 + ch;
  }

  const int T0 = (blockIdx.x * 4 + w) * 4;
  const f32x4 zero4 = {0.f, 0.f, 0.f, 0.f};

  float4 xA, yA, zA, tA, xB, yB, zB, tB;
  float4 xA2, yA2, zA2, tA2, xB2, yB2, zB2, tB2;
  LOAD_IN(T0 + 0, xA, yA, zA, tA)
  LOAD_IN(T0 + 1, xB, yB, zB, tB)

  PAIR(T0, xA,yA,zA,tA, xB,yB,zB,tB,
       LOAD_IN(T0 + 2, xA2, yA2, zA2, tA2)
       LOAD_IN(T0 + 3, xB2, yB2, zB2, tB2))

  PAIR(T0 + 2, xA2,yA2,zA2,tA2, xB2,yB2,zB2,tB2, )
}

extern "C" void kernel_launch(void* const* d_in, const int* in_sizes, int n_in,
                              void* d_out, int out_size, void* d_ws, size_t ws_size,
                              hipStream_t stream) {
  P p;
  p.yW0 = (const float*)d_in[4];  p.yWs = (const float*)d_in[5];  p.yb  = (const float*)d_in[6];
  p.zW0 = (const float*)d_in[7];  p.zWs = (const float*)d_in[8];  p.zb  = (const float*)d_in[9];
  p.tW0 = (const float*)d_in[10]; p.tWs = (const float*)d_in[11]; p.tb  = (const float*)d_in[12];
  p.x0W = (const float*)d_in[13]; p.x0b = (const float*)d_in[14];
  p.y0W = (const float*)d_in[15]; p.y0b = (const float*)d_in[16];
  p.z0W = (const float*)d_in[17]; p.z0b = (const float*)d_in[18];
  p.t0W = (const float*)d_in[19]; p.t0b = (const float*)d_in[20];
  p.xWs = (const float*)d_in[21]; p.xb  = (const float*)d_in[22];
  p.xsW = (const float*)d_in[23]; p.xsb = (const float*)d_in[24];
  p.xyW = (const float*)d_in[25]; p.xyb = (const float*)d_in[26];
  p.xzW = (const float*)d_in[27]; p.xzb = (const float*)d_in[28];
  p.xtW = (const float*)d_in[29]; p.xtb = (const float*)d_in[30];
  p.fW  = (const float*)d_in[31]; p.fb  = (const float*)d_in[32];

  u32* Abuf = (u32*)d_ws;
  prep_kernel<<<8, 256, 0, stream>>>(p, Abuf);

  const float* x0 = (const float*)d_in[0];
  const float* y0 = (const float*)d_in[1];
  const float* z0 = (const float*)d_in[2];
  const float* t0 = (const float*)d_in[3];

  const int n = in_sizes[0] / 16;          // 1048576 rows
  const int blocks = n / 256;              // 4 waves x (2x2) tiles x 16 rows
  isnn_fwd<<<blocks, 256, 0, stream>>>(x0, y0, z0, t0, Abuf, (float*)d_out);
}

// Round 8
// 144.394 us; speedup vs baseline: 2.0695x; 1.0505x over previous
//
#include <hip/hip_runtime.h>
#include <hip/hip_bf16.h>

typedef short s8v  __attribute__((ext_vector_type(8)));
typedef float f32x4 __attribute__((ext_vector_type(4)));
typedef unsigned int u32;
typedef u32 u32x4 __attribute__((ext_vector_type(4)));

#define NSLOT 31

// ---------- bf16 helpers (RNE) ----------
__device__ __forceinline__ unsigned short b16hi(float v) {
  unsigned int u = __float_as_uint(v);
  return (unsigned short)((u + 0x7FFFu + ((u >> 16) & 1u)) >> 16);
}
__device__ __forceinline__ float b16tof(unsigned short h) {
  return __uint_as_float(((unsigned int)h) << 16);
}
__device__ __forceinline__ unsigned short lobits(float w) {
  return b16hi(w - b16tof(b16hi(w)));
}
__device__ __forceinline__ float sp_stable(float v) {
  float ax = __builtin_fabsf(v);
  float e  = __expf(-ax);
  return fmaxf(v, 0.0f) + __logf(1.0f + e);
}
__device__ __forceinline__ float sigmoid_f(float v) {
  return __builtin_amdgcn_rcpf(1.0f + __expf(-v));
}

// =====================================================================
// PREP (identical to R6/R7, verified): A-frags for D = W . act^T
// lane l: m = l&15, k = 4*(l>>4)+{0..3} (dw0,1) and 16+4*(l>>4)+{0..3} (dw2,3)
// =====================================================================
struct P {
  const float *yW0,*yWs,*yb,*zW0,*zWs,*zb,*tW0,*tWs,*tb;
  const float *x0W,*x0b,*y0W,*y0b,*z0W,*z0b,*t0W,*t0b;
  const float *xWs,*xb,*xsW,*xsb,*xyW,*xyb,*xzW,*xzb,*xtW,*xtb,*fW,*fb;
};

__device__ unsigned short pat15(const float* W, const float* b, int k, int j, int sp) {
  if (k < 15)  { float v = W[j*15+k];      return b16hi(sp ? sp_stable(v) : v); }
  if (k == 15) return b ? b16hi(b[j]) : (unsigned short)0;
  if (k < 31)  { float v = W[j*15+(k-16)]; return lobits(sp ? sp_stable(v) : v); }
  return b ? lobits(b[j]) : (unsigned short)0;
}

__device__ unsigned short wA(int s, int k, int j, const P& p) {
  if (j > 14) return 0;
  if (s == 0) {
    if (k < 8)   return b16hi(sp_stable(p.yW0[j*8+k]));
    if (k < 16)  return lobits(sp_stable(p.yW0[j*8+(k-8)]));
    if (k == 16) return b16hi(p.yb[j]);
    if (k == 17) return lobits(p.yb[j]);
    return 0;
  }
  if (s <= 3)  return pat15(p.yWs + (s-1)*225, p.yb + s*15, k, j, 1);
  if (s == 4) {
    if (k < 8)   return b16hi(p.zW0[j*8+k]);
    if (k < 16)  return lobits(p.zW0[j*8+(k-8)]);
    if (k == 16) return b16hi(p.zb[j]);
    if (k == 17) return lobits(p.zb[j]);
    return 0;
  }
  if (s <= 7)  return pat15(p.zWs + (s-5)*225, p.zb + (s-4)*15, k, j, 0);
  if (s == 8) {
    if (k < 4)   return b16hi(sp_stable(p.tW0[j*4+k]));
    if (k < 8)   return lobits(sp_stable(p.tW0[j*4+(k-4)]));
    if (k == 8)  return b16hi(p.tb[j]);
    if (k == 9)  return lobits(p.tb[j]);
    return 0;
  }
  if (s <= 11) return pat15(p.tWs + (s-9)*225, p.tb + (s-8)*15, k, j, 1);
  if (s == 12) {
    if (k < 16) return b16hi(p.x0W[j*16+k]);
    return lobits(p.x0W[j*16+(k-16)]);
  }
  if (s == 13) {
    if (k < 8)  return b16hi(sp_stable(p.y0W[j*8+k]));
    if (k < 16) return b16hi(p.z0W[j*8+(k-8)]);
    if (k < 24) return lobits(sp_stable(p.y0W[j*8+(k-16)]));
    return lobits(p.z0W[j*8+(k-24)]);
  }
  if (s == 14) {
    if (k < 4)  return b16hi(sp_stable(p.t0W[j*4+k]));
    if (k < 8)  return lobits(sp_stable(p.t0W[j*4+(k-4)]));
    float xfb = p.x0b[j] + p.y0b[j] + p.z0b[j] + p.t0b[j];
    if (k == 8) return b16hi(xfb);
    if (k == 9) return lobits(xfb);
    return 0;
  }
  if (s <= 29) {
    int i = (s-15)/5, r = (s-15)%5;
    if (r == 0) {
      if (k == 15 || k == 31) {
        float xlb = p.xb[i*15+j] + p.xsb[i*15+j] + p.xyb[i*15+j]
                  + p.xzb[i*15+j] + p.xtb[i*15+j];
        return (k == 15) ? b16hi(xlb) : lobits(xlb);
      }
      return pat15(p.xWs + i*225, nullptr, k, j, 1);
    }
    if (r == 1) {
      const float* W = p.xsW + i*240;
      if (k < 16) return b16hi(W[j*16+k]);
      return lobits(W[j*16+(k-16)]);
    }
    if (r == 2) return pat15(p.xyW + i*225, nullptr, k, j, 1);
    if (r == 3) return pat15(p.xzW + i*225, nullptr, k, j, 0);
    return pat15(p.xtW + i*225, nullptr, k, j, 1);
  }
  return pat15(p.fW, p.fb, k, j, 0);   // s == 30
}

__global__ void prep_kernel(P p, u32* Abuf) {
  const int tid = blockIdx.x * blockDim.x + threadIdx.x;
  const int str = gridDim.x * blockDim.x;
  for (int idx = tid; idx < NSLOT*256; idx += str) {
    int s = idx >> 8, rem = idx & 255, l = rem >> 2, d = rem & 3;
    int g = l >> 4, j = l & 15;
    int kb = (d < 2) ? (4*g + 2*d) : (16 + 4*g + 2*(d-2));
    u32 v0 = wA(s, kb,   j, p);
    u32 v1 = wA(s, kb+1, j, p);
    Abuf[idx] = v0 | (v1 << 16);
  }
}

// =====================================================================
// MAIN: weights in per-block LDS (ds_read_b128 per use, offset-immediate);
// registers freed -> 4 waves/SIMD; TLP hides MFMA/trans latency.
// Numerics identical to R6/R7.
// =====================================================================
union FragU { u32x4 u; s8v s; };
__device__ __forceinline__ s8v mkfrag(u32 a, u32 b, u32 c, u32 d) {
  FragU f; f.u = u32x4{a, b, c, d}; return f.s;
}
__device__ __forceinline__ u32 pk(float lo, float hi) {
  union { __hip_bfloat162 h; u32 u; } cv;
  cv.h = __float22bfloat162_rn(float2{lo, hi});
  return cv.u;
}
__device__ __forceinline__ float lo16f(u32 u) { return __uint_as_float(u << 16); }
__device__ __forceinline__ float hi16f(u32 u) { return __uint_as_float(u & 0xFFFF0000u); }

#define MFMA(A,B,C) __builtin_amdgcn_mfma_f32_16x16x32_bf16((A),(B),(C),0,0,0)
#define ONE2 0x3F803F80u

__device__ __forceinline__ void act_sp(f32x4 a, int g,
                                       u32& h0, u32& h1, u32& l0, u32& l1) {
  float v0 = sp_stable(a[0]), v1 = sp_stable(a[1]);
  float v2 = sp_stable(a[2]), v3 = sp_stable(a[3]);
  h0 = pk(v0, v1);
  u32 h1u = pk(v2, v3);
  l0 = pk(v0 - lo16f(h0),  v1 - hi16f(h0));
  l1 = pk(v2 - lo16f(h1u), v3 - hi16f(h1u));
  h1 = (g == 3) ? ((h1u & 0xFFFFu) | 0x3F800000u) : h1u;
  l1 = (g == 3) ? (l1 & 0xFFFFu) : l1;
}
__device__ __forceinline__ void act_sig(f32x4 a, int g, u32& d0, u32& d1) {
  d0 = pk(sigmoid_f(a[0]), sigmoid_f(a[1]));
  u32 d1u = pk(sigmoid_f(a[2]), sigmoid_f(a[3]));
  d1 = (g == 3) ? ((d1u & 0xFFFFu) | 0x3F800000u) : d1u;
}

__global__ __launch_bounds__(256, 4) void isnn_fwd(
    const float* __restrict__ x0g, const float* __restrict__ y0g,
    const float* __restrict__ z0g, const float* __restrict__ t0g,
    const u32* __restrict__ Abuf, float* __restrict__ outg)
{
  __shared__ u32x4 wlds[NSLOT*64];        // 31 KiB weight frags (block-shared)
  __shared__ float olds[4][320];          // per-wave out staging (5 KiB)

  const int tid = threadIdx.x;
  // ---- stage weight frags into LDS once per block
  for (int i = tid; i < NSLOT*64; i += 256) wlds[i] = ((const u32x4*)Abuf)[i];
  __syncthreads();

  const int lane = tid & 63;
  const int w    = tid >> 6;
  const int g    = lane >> 4;
  const int c    = lane & 15;

  // per-lane LDS base; AW(s) compiles to one ds_read_b128 with offset:s*1024
  const char* wbase = (const char*)wlds + lane * 16;
#define AW(s) (*(const s8v*)(wbase + (s)*1024))

  // ---- coalesced-store index precompute (240 floats per tile)
  int oidx[4]; bool oon[4];
#pragma unroll
  for (int jj = 0; jj < 4; ++jj) {
    int i = lane + 64*jj;
    oon[jj]  = (i < 240);
    int row  = i / 15, ch = i - row*15;
    oidx[jj] = row*20 + ch;
  }

  const int T0 = (blockIdx.x * 4 + w) * 4;
  const f32x4 zero4 = {0.f, 0.f, 0.f, 0.f};

  // ---- input regs (tile prefetch pipeline); wave reads 1KiB contiguous
  float4 x4 = ((const float4*)x0g)[(size_t)(T0*16 + c)*4 + g];
  float4 y4 = ((const float4*)y0g)[(size_t)(T0*16 + c)*2 + (g & 1)];
  float4 z4 = ((const float4*)z0g)[(size_t)(T0*16 + c)*2 + (g & 1)];
  float4 t4 = ((const float4*)t0g)[(size_t)(T0*16 + c)];

#pragma unroll
  for (int it = 0; it < 4; ++it) {
    const int T = T0 + it;

    // ---- build input B-frags
    u32 dx0 = pk(x4.x, x4.y), dx1 = pk(x4.z, x4.w);
    u32 dy0 = pk(y4.x, y4.y), dy1 = pk(y4.z, y4.w);
    u32 dz0 = pk(z4.x, z4.y), dz1 = pk(z4.z, z4.w);
    u32 dt0 = pk(t4.x, t4.y), dt1 = pk(t4.z, t4.w);
    u32 bsl = (g == 0) ? ONE2 : 0u;
    s8v Bx0 = mkfrag(dx0, dx1, dx0, dx1);
    s8v By0 = mkfrag(dy0, dy1, bsl, 0u);
    s8v Bz0 = mkfrag(dz0, dz1, bsl, 0u);
    s8v Bt0 = mkfrag((g < 2) ? dt0 : ((g == 2) ? ONE2 : 0u),
                     (g < 2) ? dt1 : 0u, 0u, 0u);
    u32 syz0 = (g < 2) ? dy0 : dz0, syz1 = (g < 2) ? dy1 : dz1;
    s8v Byz = mkfrag(syz0, syz1, syz0, syz1);

    // ---- prefetch next tile's inputs
    if (it < 3) {
      x4 = ((const float4*)x0g)[(size_t)((T+1)*16 + c)*4 + g];
      y4 = ((const float4*)y0g)[(size_t)((T+1)*16 + c)*2 + (g & 1)];
      z4 = ((const float4*)z0g)[(size_t)((T+1)*16 + c)*2 + (g & 1)];
      t4 = ((const float4*)t0g)[(size_t)((T+1)*16 + c)];
    }

    // ---- towers layer 1
    f32x4 aY = MFMA(AW(0), By0, zero4);
    f32x4 aZ = MFMA(AW(4), Bz0, zero4);
    f32x4 aT = MFMA(AW(8), Bt0, zero4);

    // ---- towers layers 2..4
    u32 yh0, yh1, yl0, yl1, zf0, zf1, tf0, tf1;
#pragma unroll
    for (int l = 0; l < 3; ++l) {
      act_sp(aY, g, yh0, yh1, yl0, yl1);
      act_sig(aZ, g, zf0, zf1);
      act_sig(aT, g, tf0, tf1);
      s8v ay = AW(1+l);
      aY = MFMA(ay, mkfrag(yh0, yh1, yh0, yh1), zero4);
      aY = MFMA(ay, mkfrag(yl0, yl1, 0u, 0u), aY);
      aZ = MFMA(AW(5+l), mkfrag(zf0, zf1, zf0, zf1), zero4);
      aT = MFMA(AW(9+l), mkfrag(tf0, tf1, tf0, tf1), zero4);
    }
    act_sp(aY, g, yh0, yh1, yl0, yl1);
    act_sig(aZ, g, zf0, zf1);
    act_sig(aT, g, tf0, tf1);
    s8v FyH = mkfrag(yh0, yh1, yh0, yh1);
    s8v FyL = mkfrag(yl0, yl1, 0u, 0u);
    s8v Fz  = mkfrag(zf0, zf1, zf0, zf1);
    s8v Ft  = mkfrag(tf0, tf1, tf0, tf1);

    // ---- x first block
    f32x4 aX = MFMA(AW(12), Bx0, zero4);
    aX = MFMA(AW(13), Byz, aX);
    aX = MFMA(AW(14), Bt0, aX);

    // ---- 3 x iterations
    u32 xh0, xh1, xl0, xl1;
#pragma unroll
    for (int i = 0; i < 3; ++i) {
      act_sp(aX, g, xh0, xh1, xl0, xl1);
      s8v ax = AW(15+5*i);
      aX = MFMA(ax, mkfrag(xh0, xh1, xh0, xh1), zero4);
      aX = MFMA(ax, mkfrag(xl0, xl1, 0u, 0u), aX);
      aX = MFMA(AW(16+5*i), Bx0, aX);
      s8v axy = AW(17+5*i);
      aX = MFMA(axy, FyH, aX);
      aX = MFMA(axy, FyL, aX);
      aX = MFMA(AW(18+5*i), Fz, aX);
      aX = MFMA(AW(19+5*i), Ft, aX);
    }

    // ---- final linear
    act_sp(aX, g, xh0, xh1, xl0, xl1);
    s8v af = AW(30);
    f32x4 aO = MFMA(af, mkfrag(xh0, xh1, xh0, xh1), zero4);
    aO = MFMA(af, mkfrag(xl0, xl1, 0u, 0u), aO);

    // ---- coalesced store via tiny LDS transpose
    *(f32x4*)(&olds[w][c*20 + 4*g]) = aO;
    float* orow = outg + (size_t)T * 240;
#pragma unroll
    for (int jj = 0; jj < 4; ++jj)
      if (oon[jj]) orow[lane + 64*jj] = olds[w][oidx[jj]];
  }
#undef AW
}

extern "C" void kernel_launch(void* const* d_in, const int* in_sizes, int n_in,
                              void* d_out, int out_size, void* d_ws, size_t ws_size,
                              hipStream_t stream) {
  P p;
  p.yW0 = (const float*)d_in[4];  p.yWs = (const float*)d_in[5];  p.yb  = (const float*)d_in[6];
  p.zW0 = (const float*)d_in[7];  p.zWs = (const float*)d_in[8];  p.zb  = (const float*)d_in[9];
  p.tW0 = (const float*)d_in[10]; p.tWs = (const float*)d_in[11]; p.tb  = (const float*)d_in[12];
  p.x0W = (const float*)d_in[13]; p.x0b = (const float*)d_in[14];
  p.y0W = (const float*)d_in[15]; p.y0b = (const float*)d_in[16];
  p.z0W = (const float*)d_in[17]; p.z0b = (const float*)d_in[18];
  p.t0W = (const float*)d_in[19]; p.t0b = (const float*)d_in[20];
  p.xWs = (const float*)d_in[21]; p.xb  = (const float*)d_in[22];
  p.xsW = (const float*)d_in[23]; p.xsb = (const float*)d_in[24];
  p.xyW = (const float*)d_in[25]; p.xyb = (const float*)d_in[26];
  p.xzW = (const float*)d_in[27]; p.xzb = (const float*)d_in[28];
  p.xtW = (const float*)d_in[29]; p.xtb = (const float*)d_in[30];
  p.fW  = (const float*)d_in[31]; p.fb  = (const float*)d_in[32];

  u32* Abuf = (u32*)d_ws;
  prep_kernel<<<8, 256, 0, stream>>>(p, Abuf);

  const float* x0 = (const float*)d_in[0];
  const float* y0 = (const float*)d_in[1];
  const float* z0 = (const float*)d_in[2];
  const float* t0 = (const float*)d_in[3];

  const int n = in_sizes[0] / 16;          // 1048576 rows
  const int blocks = n / 256;              // 4 waves x 4 tiles x 16 rows
  isnn_fwd<<<blocks, 256, 0, stream>>>(x0, y0, z0, t0, Abuf, (float*)d_out);
}